// Round 20
// baseline (137.957 us; speedup 1.0000x reference)
//
#include <hip/hip_runtime.h>
#include <hip/hip_fp16.h>

static constexpr float SLOPE = 0.2f;

#define NPB 256          // nodes per bucket
#define NBMAX 512        // max buckets
#define CAP 10240        // packed-edge capacity per bucket (avg ~8184, >20 sigma margin)
#define EPB 8192         // edges per bin block (~21 words/bucket region, line-coalesced)

// ---------------------------------------------------------------------------
// Monotone float<->uint key for exact atomicMax on floats of either sign.
__device__ __forceinline__ unsigned fkey(float f) {
    unsigned u = __float_as_uint(f);
    return (u & 0x80000000u) ? ~u : (u | 0x80000000u);
}
__device__ __forceinline__ float fdekey(unsigned k) {
    unsigned u = (k & 0x80000000u) ? (k & 0x7FFFFFFFu) : ~k;
    return __uint_as_float(u);
}

__device__ __forceinline__ int load_idx(const void* ei, int is64, long long pos) {
    return is64 ? (int)((const long long*)ei)[pos] : ((const int*)ei)[pos];
}

// ---------------------------------------------------------------------------
// Zero the gkeys + bfill workspace (replaces hipMemsetAsync fill node).
__global__ void zero_kernel(unsigned* __restrict__ gkeys, int* __restrict__ bfill) {
    int t = threadIdx.x;
    if (t < 2) gkeys[t] = 0u;
    for (int i = t; i < NBMAX; i += 256) bfill[i] = 0;
}

// ---------------------------------------------------------------------------
// Pass 1: bin edges by dst bucket. LDS-staged sort-by-bucket write-out:
// histogram -> block-local scan -> place into LDS sorted by bucket -> bulk
// reserve -> linear coalesced write-out (writes ~ payload + boundary
// fragments). 1024-thread blocks (16 waves) for latency hiding; EPB=8192
// keeps ~21 contiguous words per bucket region per block. int32 path uses
// contiguous uint4 vector loads (8 edges/thread). Order within a bucket
// region is schedule-dependent; harmless because aggregation is bitwise
// order-independent. int64-vs-int32 edge dtype detected inline (wave-0
// ballot over high words, L2-hot).
__global__ void __launch_bounds__(1024) bin_kernel(
        const void* __restrict__ ei, int* __restrict__ bfill,
        unsigned int* __restrict__ packed, int e, int nb) {
    __shared__ int hist[NBMAX];            // counts, then gbase after reserve
    __shared__ int lbase[NBMAX];           // local exclusive scan
    __shared__ int cur[NBMAX];             // placement cursor
    __shared__ unsigned staged[EPB];       // 32KB bucket-sorted packed words
    __shared__ unsigned short sbkt[EPB];   // 16KB bucket id per slot
    __shared__ int sflag;
    int t = threadIdx.x;
    if (t < 64) {
        unsigned hi = ((const unsigned*)ei)[2 * t + 1];
        unsigned long long b = __ballot(hi != 0u);
        if (t == 0) sflag = (b == 0ull) ? 1 : 0;
    }
    if (t < NBMAX) hist[t] = 0;
    __syncthreads();
    int is64 = sflag;
    long long e0 = (long long)blockIdx.x * EPB;
    int cnt = (int)min((long long)EPB, (long long)e - e0);
    // phase A: load 8 contiguous edges/thread into registers + histogram
    int sr[8], dr[8];
    if (!is64 && t * 8 + 7 < cnt) {
        const uint4* ps = (const uint4*)((const int*)ei + e0) + t * 2;
        const uint4* pd = (const uint4*)((const int*)ei + e + e0) + t * 2;
        uint4 s0 = ps[0], s1 = ps[1], d0 = pd[0], d1 = pd[1];
        sr[0] = s0.x; sr[1] = s0.y; sr[2] = s0.z; sr[3] = s0.w;
        sr[4] = s1.x; sr[5] = s1.y; sr[6] = s1.z; sr[7] = s1.w;
        dr[0] = d0.x; dr[1] = d0.y; dr[2] = d0.z; dr[3] = d0.w;
        dr[4] = d1.x; dr[5] = d1.y; dr[6] = d1.z; dr[7] = d1.w;
    } else {
#pragma unroll
        for (int r = 0; r < 8; ++r) {
            int i = t * 8 + r;
            dr[r] = -1;
            if (i < cnt) {
                sr[r] = load_idx(ei, is64, e0 + i);
                dr[r] = load_idx(ei, is64, (long long)e + e0 + i);
            }
        }
    }
#pragma unroll
    for (int r = 0; r < 8; ++r)
        if (dr[r] >= 0) atomicAdd(&hist[dr[r] >> 8], 1);
    __syncthreads();
    // block-local exclusive scan over NBMAX buckets (thread t owns bucket t)
    int v = (t < NBMAX) ? hist[t] : 0;
    if (t < NBMAX) lbase[t] = v;
    __syncthreads();
    for (int off = 1; off < NBMAX; off <<= 1) {
        int y = (t < NBMAX && t >= off) ? lbase[t - off] : 0;
        __syncthreads();
        if (t < NBMAX) lbase[t] += y;
        __syncthreads();
    }
    if (t < NBMAX) {
        lbase[t] -= v;          // exclusive
        cur[t] = lbase[t];
        hist[t] = (v > 0) ? atomicAdd(&bfill[t], v) : 0;  // hist becomes gbase
    }
    __syncthreads();
    // phase B: place into LDS staged, sorted by bucket
#pragma unroll
    for (int r = 0; r < 8; ++r) {
        if (dr[r] >= 0) {
            int bk = dr[r] >> 8;
            int lp = atomicAdd(&cur[bk], 1);
            staged[lp] = ((unsigned)(dr[r] & 255) << 17) | (unsigned)sr[r];
            sbkt[lp] = (unsigned short)bk;
        }
    }
    __syncthreads();
    // phase C: coalesced linear write-out
    for (int i = t; i < cnt; i += 1024) {
        int bk = sbkt[i];
        int within = hist[bk] + (i - lbase[bk]);
        if (within < CAP)
            packed[(long long)bk * CAP + within] = staged[i];
    }
}

// ---------------------------------------------------------------------------
// Per-node feature transform: h = x @ W; alpha_src = h . a_src; alpha_dst = h . a_dst
// Writes h in fp32 (exact: self-term, next layer input) AND fp16 (h16, the
// 3.2MB gather table that fits per-XCD L2). Attention scores as/ad stay fp32.
// Also computes the EXACT global max of alpha_src (order-free) via uint-keyed
// atomicMax — used by aggr_kernel as a softmax upper bound.
template <int NF>
__global__ void feat_kernel(const float* __restrict__ x, const float* __restrict__ W,
                            const float* __restrict__ avs, const float* __restrict__ avd,
                            float* __restrict__ h, __half* __restrict__ h16,
                            float* __restrict__ as, float* __restrict__ ad,
                            unsigned* __restrict__ gkey, int n) {
    __shared__ float sW[NF * 16];
    __shared__ float sa[32];
    __shared__ float red[256];
    int t = threadIdx.x;
    if (t < NF * 16) sW[t] = W[t];
    if (t < 16) sa[t] = avs[t];
    else if (t < 32) sa[t] = avd[t - 16];
    __syncthreads();
    int nid = blockIdx.x * blockDim.x + t;
    float s1 = -1e30f;
    if (nid < n) {
        float xi[NF];
#pragma unroll
        for (int f = 0; f < NF; ++f) xi[f] = x[(long long)nid * NF + f];
        float hv[16];
        s1 = 0.f;
        float s2 = 0.f;
#pragma unroll
        for (int k = 0; k < 16; ++k) {
            float acc = 0.f;
#pragma unroll
            for (int f = 0; f < NF; ++f) acc = fmaf(xi[f], sW[f * 16 + k], acc);
            hv[k] = acc;
            s1 = fmaf(acc, sa[k], s1);
            s2 = fmaf(acc, sa[16 + k], s2);
        }
        float4* hp = (float4*)(h + (long long)nid * 16);
        hp[0] = make_float4(hv[0], hv[1], hv[2], hv[3]);
        hp[1] = make_float4(hv[4], hv[5], hv[6], hv[7]);
        hp[2] = make_float4(hv[8], hv[9], hv[10], hv[11]);
        hp[3] = make_float4(hv[12], hv[13], hv[14], hv[15]);
        // fp16 row (32B, two 16B stores)
        unsigned u[8];
#pragma unroll
        for (int q = 0; q < 8; ++q) {
            __half2 p2 = __halves2half2(__float2half(hv[2 * q]), __float2half(hv[2 * q + 1]));
            u[q] = *(unsigned*)&p2;
        }
        uint4* hp16 = (uint4*)(h16 + (long long)nid * 16);
        hp16[0] = make_uint4(u[0], u[1], u[2], u[3]);
        hp16[1] = make_uint4(u[4], u[5], u[6], u[7]);
        as[nid] = s1;
        ad[nid] = s2;
    }
    red[t] = s1;
    __syncthreads();
    for (int off = 128; off > 0; off >>= 1) {
        if (t < off) red[t] = fmaxf(red[t], red[t + off]);
        __syncthreads();
    }
    if (t == 0) atomicMax(gkey, fkey(red[0]));
}

// ---------------------------------------------------------------------------
// EDGE-PARALLEL softmax aggregation, one 1024-thread block (16 waves) per
// bucket, straight from the packed (dst_local<<17|src) array. Each thread
// owns whole edges (64 independent edges per wave): 1 packed load + 1 as
// gather + ONE vectorized 32B h16-row load (2x uint4), then 17 fire-and-
// forget LDS int64 atomics (ds_add_u64 has no return => no wave stall; edge
// iterations are fully independent => 16 waves/block give ~24 waves/CU of
// gather-latency overlap at grid 391). acc stride is 17 qwords/node to break
// the 128B bank wrap => (dl+k)%16 bank-pair spread. Self term folded into
// the init phase from exact fp32 h. BITWISE ORDER-INDEPENDENT: integer
// atomic adds commute exactly => identical result for ANY edge order or
// schedule; normalizer m = leaky(gmax+adn) is a global bound (LeakyReLU
// monotone) so exp args <= 0; per-node exponent boost kb keeps den >= ~2^20
// (quantization ~1e-4, terms < 2^31).
__global__ void __launch_bounds__(1024) aggr_kernel(
        const float* __restrict__ h, const __half* __restrict__ h16,
        const float* __restrict__ as, const float* __restrict__ ad,
        const unsigned* __restrict__ packed, const int* __restrict__ bfill,
        const float* __restrict__ bias, const unsigned* __restrict__ gkey,
        float* __restrict__ out, int n, int do_relu) {
    __shared__ unsigned long long accS[NPB * 17];  // 34816 B, stride 17 anti-conflict
    __shared__ unsigned long long denS[NPB];       // 2 KB
    __shared__ float ccS[NPB];                     // 1 KB
    __shared__ float adnS[NPB];                    // 1 KB
    int b = blockIdx.x, t = threadIdx.x;
    float gmax = fdekey(*gkey);
    // init: per-node state + self term (threads 0..255, one node each)
    if (t < NPB) {
        int node = b * NPB + t;
        if (node < n) {
            float adn = ad[node];
            adnS[t] = adn;
            float gm = gmax + adn;
            float m = fmaxf(gm, SLOPE * gm);       // leaky(gmax + adn)
            float es = as[node] + adn;
            es = fmaxf(es, SLOPE * es);
            float kb = fminf(7.f, fmaxf(0.f, floorf((m - es) * 1.44269504f)));
            float cc = (21.f + kb) * 0.69314718f - m;
            ccS[t] = cc;
            float ws = __expf(es + cc);
            denS[t] = (unsigned long long)(long long)(int)ws;
            const float4* hp = (const float4*)(h + (long long)node * 16);
            float4 h0 = hp[0], h1v = hp[1], h2v = hp[2], h3v = hp[3];
            float hv[16] = {h0.x, h0.y, h0.z, h0.w, h1v.x, h1v.y, h1v.z, h1v.w,
                            h2v.x, h2v.y, h2v.z, h2v.w, h3v.x, h3v.y, h3v.z, h3v.w};
#pragma unroll
            for (int k = 0; k < 16; ++k)
                accS[t * 17 + k] = (unsigned long long)(long long)(int)(ws * hv[k]);
        }
    }
    __syncthreads();
    // edge-parallel accumulation (iterations independent — atomics return
    // nothing, so waves overlap the packed/as/h16 gather chains freely)
    int cnt = min(bfill[b], CAP);
    long long pb = (long long)b * CAP;
#pragma unroll 2
    for (int j = t; j < cnt; j += 1024) {
        unsigned p = packed[pb + j];
        int dl = p >> 17;
        int s = (int)(p & 0x1FFFF);
        float e2 = as[s] + adnS[dl];
        e2 = fmaxf(e2, SLOPE * e2);
        float w = __expf(e2 + ccS[dl]);
        atomicAdd(&denS[dl], (unsigned long long)(long long)(int)w);
        const uint4* hr = (const uint4*)(h16 + (long long)s * 16);
        uint4 r0 = hr[0], r1 = hr[1];
        unsigned rr[8] = {r0.x, r0.y, r0.z, r0.w, r1.x, r1.y, r1.z, r1.w};
        int base = dl * 17;
#pragma unroll
        for (int q = 0; q < 8; ++q) {
            __half2 h2 = *(__half2*)&rr[q];
            float2 f = __half22float2(h2);
            atomicAdd(&accS[base + 2 * q],
                      (unsigned long long)(long long)(int)(w * f.x));
            atomicAdd(&accS[base + 2 * q + 1],
                      (unsigned long long)(long long)(int)(w * f.y));
        }
    }
    __syncthreads();
    // output: divide + bias (+ relu), coalesced
    for (int idx = t; idx < NPB * 16; idx += 1024) {
        int i = idx >> 4, k = idx & 15;
        int node = b * NPB + i;
        if (node < n) {
            float o = (float)(long long)accS[i * 17 + k] /
                      (float)(long long)denS[i] + bias[k];
            if (do_relu) o = fmaxf(o, 0.f);
            out[(long long)node * 16 + k] = o;
        }
    }
}

// ---------------------------------------------------------------------------
extern "C" void kernel_launch(void* const* d_in, const int* in_sizes, int n_in,
                              void* d_out, int out_size, void* d_ws, size_t ws_size,
                              hipStream_t stream) {
    const float* x  = (const float*)d_in[0];
    const void*  ei = d_in[1];
    const float* W1  = (const float*)d_in[2];
    const float* as1 = (const float*)d_in[3];
    const float* ad1 = (const float*)d_in[4];
    const float* b1  = (const float*)d_in[5];
    const float* W2  = (const float*)d_in[6];
    const float* as2 = (const float*)d_in[7];
    const float* ad2 = (const float*)d_in[8];
    const float* b2  = (const float*)d_in[9];
    float* out = (float*)d_out;

    const int n = in_sizes[0] / 14;      // 100000
    const int e = in_sizes[1] / 2;       // 3200000
    const int nb = (n + NPB - 1) / NPB;  // 391 buckets

    char* p = (char*)d_ws;
    auto alloc = [&](size_t bytes) {
        char* r = p;
        p += (bytes + 255) & ~(size_t)255;
        return r;
    };
    unsigned* gkeys  = (unsigned*)alloc(256);          // [0]=gkey1, [1]=gkey2
    int*      bfill  = (int*)alloc(NBMAX * 4);
    unsigned* packed = (unsigned*)alloc((size_t)nb * CAP * 4);
    float*    h      = (float*)alloc((size_t)n * 16 * 4);
    __half*   h16    = (__half*)alloc((size_t)n * 16 * 2);
    float*    h1     = (float*)alloc((size_t)n * 16 * 4);
    float*    asb    = (float*)alloc((size_t)n * 4);
    float*    adb    = (float*)alloc((size_t)n * 4);

    zero_kernel<<<1, 256, 0, stream>>>(gkeys, bfill);
    bin_kernel<<<(e + EPB - 1) / EPB, 1024, 0, stream>>>(ei, bfill, packed, e, nb);

    // Layer 1
    feat_kernel<14><<<(n + 255) / 256, 256, 0, stream>>>(x, W1, as1, ad1, h, h16, asb, adb, gkeys + 0, n);
    aggr_kernel<<<nb, 1024, 0, stream>>>(h, h16, asb, adb, packed, bfill, b1, gkeys + 0, h1, n, 1);
    // Layer 2
    feat_kernel<16><<<(n + 255) / 256, 256, 0, stream>>>(h1, W2, as2, ad2, h, h16, asb, adb, gkeys + 1, n);
    aggr_kernel<<<nb, 1024, 0, stream>>>(h, h16, asb, adb, packed, bfill, b2, gkeys + 1, out, n, 0);
}

// Round 21
// 120.841 us; speedup vs baseline: 1.1416x; 1.1416x over previous
//
#include <hip/hip_runtime.h>
#include <hip/hip_fp16.h>

static constexpr float SLOPE = 0.2f;

#define NPB 256          // nodes per bucket
#define NBMAX 512        // max buckets
#define CAP 10240        // packed-edge capacity per bucket (avg ~8184, >20 sigma margin)
#define EPB 8192         // edges per bin block (~21 words/bucket region, line-coalesced)

// ---------------------------------------------------------------------------
// Monotone float<->uint key for exact atomicMax on floats of either sign.
__device__ __forceinline__ unsigned fkey(float f) {
    unsigned u = __float_as_uint(f);
    return (u & 0x80000000u) ? ~u : (u | 0x80000000u);
}
__device__ __forceinline__ float fdekey(unsigned k) {
    unsigned u = (k & 0x80000000u) ? (k & 0x7FFFFFFFu) : ~k;
    return __uint_as_float(u);
}

__device__ __forceinline__ int load_idx(const void* ei, int is64, long long pos) {
    return is64 ? (int)((const long long*)ei)[pos] : ((const int*)ei)[pos];
}

// ---------------------------------------------------------------------------
// Zero the gkeys + bfill workspace (replaces hipMemsetAsync fill node).
__global__ void zero_kernel(unsigned* __restrict__ gkeys, int* __restrict__ bfill) {
    int t = threadIdx.x;
    if (t < 2) gkeys[t] = 0u;
    for (int i = t; i < NBMAX; i += 256) bfill[i] = 0;
}

// ---------------------------------------------------------------------------
// Pass 1: bin edges by dst bucket. LDS-staged sort-by-bucket write-out
// (histogram -> scan -> LDS place -> bulk reserve -> linear write-out).
__global__ void __launch_bounds__(1024) bin_kernel(
        const void* __restrict__ ei, int* __restrict__ bfill,
        unsigned int* __restrict__ packed, int e, int nb) {
    __shared__ int hist[NBMAX];            // counts, then gbase after reserve
    __shared__ int lbase[NBMAX];           // local exclusive scan
    __shared__ int cur[NBMAX];             // placement cursor
    __shared__ unsigned staged[EPB];       // 32KB bucket-sorted packed words
    __shared__ unsigned short sbkt[EPB];   // 16KB bucket id per slot
    __shared__ int sflag;
    int t = threadIdx.x;
    if (t < 64) {
        unsigned hi = ((const unsigned*)ei)[2 * t + 1];
        unsigned long long b = __ballot(hi != 0u);
        if (t == 0) sflag = (b == 0ull) ? 1 : 0;
    }
    if (t < NBMAX) hist[t] = 0;
    __syncthreads();
    int is64 = sflag;
    long long e0 = (long long)blockIdx.x * EPB;
    int cnt = (int)min((long long)EPB, (long long)e - e0);
    // phase A: load 8 contiguous edges/thread into registers + histogram
    int sr[8], dr[8];
    if (!is64 && t * 8 + 7 < cnt) {
        const uint4* ps = (const uint4*)((const int*)ei + e0) + t * 2;
        const uint4* pd = (const uint4*)((const int*)ei + e + e0) + t * 2;
        uint4 s0 = ps[0], s1 = ps[1], d0 = pd[0], d1 = pd[1];
        sr[0] = s0.x; sr[1] = s0.y; sr[2] = s0.z; sr[3] = s0.w;
        sr[4] = s1.x; sr[5] = s1.y; sr[6] = s1.z; sr[7] = s1.w;
        dr[0] = d0.x; dr[1] = d0.y; dr[2] = d0.z; dr[3] = d0.w;
        dr[4] = d1.x; dr[5] = d1.y; dr[6] = d1.z; dr[7] = d1.w;
    } else {
#pragma unroll
        for (int r = 0; r < 8; ++r) {
            int i = t * 8 + r;
            dr[r] = -1;
            if (i < cnt) {
                sr[r] = load_idx(ei, is64, e0 + i);
                dr[r] = load_idx(ei, is64, (long long)e + e0 + i);
            }
        }
    }
#pragma unroll
    for (int r = 0; r < 8; ++r)
        if (dr[r] >= 0) atomicAdd(&hist[dr[r] >> 8], 1);
    __syncthreads();
    // block-local exclusive scan over NBMAX buckets (thread t owns bucket t)
    int v = (t < NBMAX) ? hist[t] : 0;
    if (t < NBMAX) lbase[t] = v;
    __syncthreads();
    for (int off = 1; off < NBMAX; off <<= 1) {
        int y = (t < NBMAX && t >= off) ? lbase[t - off] : 0;
        __syncthreads();
        if (t < NBMAX) lbase[t] += y;
        __syncthreads();
    }
    if (t < NBMAX) {
        lbase[t] -= v;          // exclusive
        cur[t] = lbase[t];
        hist[t] = (v > 0) ? atomicAdd(&bfill[t], v) : 0;  // hist becomes gbase
    }
    __syncthreads();
    // phase B: place into LDS staged, sorted by bucket
#pragma unroll
    for (int r = 0; r < 8; ++r) {
        if (dr[r] >= 0) {
            int bk = dr[r] >> 8;
            int lp = atomicAdd(&cur[bk], 1);
            staged[lp] = ((unsigned)(dr[r] & 255) << 17) | (unsigned)sr[r];
            sbkt[lp] = (unsigned short)bk;
        }
    }
    __syncthreads();
    // phase C: coalesced linear write-out
    for (int i = t; i < cnt; i += 1024) {
        int bk = sbkt[i];
        int within = hist[bk] + (i - lbase[bk]);
        if (within < CAP)
            packed[(long long)bk * CAP + within] = staged[i];
    }
}

// ---------------------------------------------------------------------------
// Per-node feature transform: h = x @ W; alpha_src/alpha_dst dot products.
// Writes h in fp32 (self-term, next layer input) AND fp16 (h16, 3.2MB
// gather table). (gkey retained but unused by aggr now.)
template <int NF>
__global__ void feat_kernel(const float* __restrict__ x, const float* __restrict__ W,
                            const float* __restrict__ avs, const float* __restrict__ avd,
                            float* __restrict__ h, __half* __restrict__ h16,
                            float* __restrict__ as, float* __restrict__ ad,
                            unsigned* __restrict__ gkey, int n) {
    __shared__ float sW[NF * 16];
    __shared__ float sa[32];
    int t = threadIdx.x;
    if (t < NF * 16) sW[t] = W[t];
    if (t < 16) sa[t] = avs[t];
    else if (t < 32) sa[t] = avd[t - 16];
    __syncthreads();
    int nid = blockIdx.x * blockDim.x + t;
    if (nid >= n) return;
    float xi[NF];
#pragma unroll
    for (int f = 0; f < NF; ++f) xi[f] = x[(long long)nid * NF + f];
    float hv[16];
    float s1 = 0.f, s2 = 0.f;
#pragma unroll
    for (int k = 0; k < 16; ++k) {
        float acc = 0.f;
#pragma unroll
        for (int f = 0; f < NF; ++f) acc = fmaf(xi[f], sW[f * 16 + k], acc);
        hv[k] = acc;
        s1 = fmaf(acc, sa[k], s1);
        s2 = fmaf(acc, sa[16 + k], s2);
    }
    float4* hp = (float4*)(h + (long long)nid * 16);
    hp[0] = make_float4(hv[0], hv[1], hv[2], hv[3]);
    hp[1] = make_float4(hv[4], hv[5], hv[6], hv[7]);
    hp[2] = make_float4(hv[8], hv[9], hv[10], hv[11]);
    hp[3] = make_float4(hv[12], hv[13], hv[14], hv[15]);
    unsigned u[8];
#pragma unroll
    for (int q = 0; q < 8; ++q) {
        __half2 p2 = __halves2half2(__float2half(hv[2 * q]), __float2half(hv[2 * q + 1]));
        u[q] = *(unsigned*)&p2;
    }
    uint4* hp16 = (uint4*)(h16 + (long long)nid * 16);
    hp16[0] = make_uint4(u[0], u[1], u[2], u[3]);
    hp16[1] = make_uint4(u[4], u[5], u[6], u[7]);
    as[nid] = s1;
    ad[nid] = s2;
}

// ---------------------------------------------------------------------------
// EDGE-PARALLEL two-pass softmax aggregation, one 1024-thread block per
// bucket. ATOMIC-MINIMIZED: pass 1 computes the per-node TRUE max score via
// one LDS u32 atomicMax per edge (exact, commutative); then all weights
// w = exp(e - m_node + 21 ln2) <= 2^21, so per-node channel sums < 2^30 and
// TWO channels fit in ONE u64 atomic: enc = (t1<<32) + (t0 + 2^31) added
// mod 2^64. The addend count (tracked in den's high word) lets the output
// phase recover exact carries: s0 = signed(lo - (cnt&1)<<31), carries =
// (cnt*2^31 + s0)>>32, s1 = signed(hi - carries). 9 u64 + 1 u32 atomics per
// edge (vs 17 u64). Edge (packed,e) kept in statically-indexed regs between
// passes. BITWISE ORDER-INDEPENDENT: integer max/add commute exactly =>
// identical result for ANY edge order or schedule. den >= 2^21 always =>
// quantization error ~1.5e-5.
__global__ void __launch_bounds__(1024) aggr_kernel(
        const float* __restrict__ h, const __half* __restrict__ h16,
        const float* __restrict__ as, const float* __restrict__ ad,
        const unsigned* __restrict__ packed, const int* __restrict__ bfill,
        const float* __restrict__ bias,
        float* __restrict__ out, int n, int do_relu) {
    __shared__ unsigned long long accS[NPB * 9];  // 18KB: +0..7 ch-pairs, +8 cnt|den
    __shared__ unsigned maxS[NPB];                // 1KB fkey(per-node max e)
    __shared__ float ccS[NPB];                    // 1KB
    __shared__ float adnS[NPB];                   // 1KB
    int b = blockIdx.x, t = threadIdx.x;
    int cnt = min(bfill[b], CAP);
    long long pb = (long long)b * CAP;
    // (a) init per-node state: adn + max seeded with self score
    if (t < NPB) {
        int node = b * NPB + t;
        float adn = (node < n) ? ad[node] : 0.f;
        adnS[t] = adn;
        float es = (node < n) ? (as[node] + adn) : 0.f;
        es = fmaxf(es, SLOPE * es);
        maxS[t] = fkey(es);
    }
    __syncthreads();
    // (b) pass 1: per-node true max over edges; keep (packed,e) in regs
    unsigned pk[10];
    float ev[10];
#pragma unroll
    for (int r = 0; r < 10; ++r) {
        int j = t + r * 1024;
        pk[r] = 0xFFFFFFFFu;
        if (j < cnt) {
            unsigned p = packed[pb + j];
            int dl = p >> 17;
            int s = (int)(p & 0x1FFFF);
            float e2 = as[s] + adnS[dl];
            e2 = fmaxf(e2, SLOPE * e2);
            pk[r] = p;
            ev[r] = e2;
            atomicMax(&maxS[dl], fkey(e2));
        }
    }
    __syncthreads();
    // (c) per-node cc + self term (count starts at 1)
    if (t < NPB) {
        int node = b * NPB + t;
        if (node < n) {
            float m = fdekey(maxS[t]);
            float cc = 21.f * 0.69314718f - m;   // w = exp(e+cc) <= 2^21
            ccS[t] = cc;
            float es = as[node] + adnS[t];
            es = fmaxf(es, SLOPE * es);
            float ws = __expf(es + cc);
            unsigned wsi = (unsigned)(int)ws;
            int base = t * 9;
            const float4* hp = (const float4*)(h + (long long)node * 16);
            float4 h0 = hp[0], h1v = hp[1], h2v = hp[2], h3v = hp[3];
            float hv[16] = {h0.x, h0.y, h0.z, h0.w, h1v.x, h1v.y, h1v.z, h1v.w,
                            h2v.x, h2v.y, h2v.z, h2v.w, h3v.x, h3v.y, h3v.z, h3v.w};
#pragma unroll
            for (int q = 0; q < 8; ++q) {
                int t0 = (int)(ws * hv[2 * q]);
                int t1 = (int)(ws * hv[2 * q + 1]);
                accS[base + q] = ((unsigned long long)(unsigned)t1 << 32) +
                                 (unsigned long long)((unsigned)t0 + 0x80000000u);
            }
            accS[base + 8] = (1ull << 32) | wsi;  // count=1, den=ws
        }
    }
    __syncthreads();
    // (d) pass 2: exp + packed-pair atomics (9 u64 per edge)
#pragma unroll
    for (int r = 0; r < 10; ++r) {
        if (pk[r] != 0xFFFFFFFFu) {
            unsigned p = pk[r];
            int dl = p >> 17;
            int s = (int)(p & 0x1FFFF);
            float w = __expf(ev[r] + ccS[dl]);
            unsigned wi = (unsigned)(int)w;
            int base = dl * 9;
            atomicAdd(&accS[base + 8], (1ull << 32) | wi);
            const uint4* hr = (const uint4*)(h16 + (long long)s * 16);
            uint4 r0 = hr[0], r1 = hr[1];
            unsigned rr[8] = {r0.x, r0.y, r0.z, r0.w, r1.x, r1.y, r1.z, r1.w};
#pragma unroll
            for (int q = 0; q < 8; ++q) {
                float2 f = __half22float2(*(__half2*)&rr[q]);
                int t0 = (int)(w * f.x);
                int t1 = (int)(w * f.y);
                unsigned long long enc =
                    ((unsigned long long)(unsigned)t1 << 32) +
                    (unsigned long long)((unsigned)t0 + 0x80000000u);
                atomicAdd(&accS[base + q], enc);
            }
        }
    }
    __syncthreads();
    // (e) output: unpack pairs with exact carry recovery, divide, bias, relu
    for (int idx = t; idx < NPB * 16; idx += 1024) {
        int i = idx >> 4, k = idx & 15;
        int node = b * NPB + i;
        if (node < n) {
            unsigned long long dpack = accS[i * 9 + 8];
            unsigned kcnt = (unsigned)(dpack >> 32);
            float den = (float)(unsigned)dpack;          // sum(w) < 2^27
            unsigned long long a = accS[i * 9 + (k >> 1)];
            unsigned lo = (unsigned)a, hi = (unsigned)(a >> 32);
            int s0 = (int)(lo - (kcnt << 31));           // mod-2^32 exact
            float val;
            if ((k & 1) == 0) {
                val = (float)s0;
            } else {
                long long carries =
                    ((((long long)kcnt) << 31) + (long long)s0) >> 32;
                int s1 = (int)(hi - (unsigned)carries);
                val = (float)s1;
            }
            float o = val / den + bias[k];
            if (do_relu) o = fmaxf(o, 0.f);
            out[(long long)node * 16 + k] = o;
        }
    }
}

// ---------------------------------------------------------------------------
extern "C" void kernel_launch(void* const* d_in, const int* in_sizes, int n_in,
                              void* d_out, int out_size, void* d_ws, size_t ws_size,
                              hipStream_t stream) {
    const float* x  = (const float*)d_in[0];
    const void*  ei = d_in[1];
    const float* W1  = (const float*)d_in[2];
    const float* as1 = (const float*)d_in[3];
    const float* ad1 = (const float*)d_in[4];
    const float* b1  = (const float*)d_in[5];
    const float* W2  = (const float*)d_in[6];
    const float* as2 = (const float*)d_in[7];
    const float* ad2 = (const float*)d_in[8];
    const float* b2  = (const float*)d_in[9];
    float* out = (float*)d_out;

    const int n = in_sizes[0] / 14;      // 100000
    const int e = in_sizes[1] / 2;       // 3200000
    const int nb = (n + NPB - 1) / NPB;  // 391 buckets

    char* p = (char*)d_ws;
    auto alloc = [&](size_t bytes) {
        char* r = p;
        p += (bytes + 255) & ~(size_t)255;
        return r;
    };
    unsigned* gkeys  = (unsigned*)alloc(256);          // [0]=gkey1, [1]=gkey2 (unused)
    int*      bfill  = (int*)alloc(NBMAX * 4);
    unsigned* packed = (unsigned*)alloc((size_t)nb * CAP * 4);
    float*    h      = (float*)alloc((size_t)n * 16 * 4);
    __half*   h16    = (__half*)alloc((size_t)n * 16 * 2);
    float*    h1     = (float*)alloc((size_t)n * 16 * 4);
    float*    asb    = (float*)alloc((size_t)n * 4);
    float*    adb    = (float*)alloc((size_t)n * 4);

    zero_kernel<<<1, 256, 0, stream>>>(gkeys, bfill);
    bin_kernel<<<(e + EPB - 1) / EPB, 1024, 0, stream>>>(ei, bfill, packed, e, nb);

    // Layer 1
    feat_kernel<14><<<(n + 255) / 256, 256, 0, stream>>>(x, W1, as1, ad1, h, h16, asb, adb, gkeys + 0, n);
    aggr_kernel<<<nb, 1024, 0, stream>>>(h, h16, asb, adb, packed, bfill, b1, h1, n, 1);
    // Layer 2
    feat_kernel<16><<<(n + 255) / 256, 256, 0, stream>>>(h1, W2, as2, ad2, h, h16, asb, adb, gkeys + 1, n);
    aggr_kernel<<<nb, 1024, 0, stream>>>(h, h16, asb, adb, packed, bfill, b2, gkeys + 1 ? out : out, n, 0);
}